// Round 1
// baseline (275.463 us; speedup 1.0000x reference)
//
#include <hip/hip_runtime.h>

typedef _Float16 f16;
typedef _Float16 f16x8 __attribute__((ext_vector_type(8)));
typedef float f32x4 __attribute__((ext_vector_type(4)));

// async global->LDS, 16B per lane; LDS dest = wave-uniform base + lane*16
#define GLD16(g, l) __builtin_amdgcn_global_load_lds( \
    (const __attribute__((address_space(1))) void*)(g), \
    (__attribute__((address_space(3))) void*)(l), 16, 0, 0)

// ---------------------------------------------------------------------------
// Generic f16 MFMA GEMM: C[m][n] = sum_k A[m][k] * B[n][k]  (+ bias)
// A: [M][K] row-major f16, B: [N][K] row-major f16 (i.e. B^T input layout)
// BIAS_MODE: 0 = none, 1 = bias[col], 2 = bias[row]
// Tiles: BM=BN=128, BK=32. 256 threads = 4 waves in 2x2, each wave 64x64
// via 4x4 MFMA 16x16x32_f16. Single-buffered LDS, global_load_lds staging.
// All M,N multiples of 128 and K multiples of 32 -> no edge guards.
// ---------------------------------------------------------------------------
template <typename OutT, int BIAS_MODE>
__global__ __launch_bounds__(256, 2)
void gemm_kernel(const f16* __restrict__ A, long sA,
                 const f16* __restrict__ B, long sB,
                 void* __restrict__ Cv, long sC,
                 const float* __restrict__ bias,
                 int N, int K)
{
    OutT* C = (OutT*)Cv;
    const int tid  = threadIdx.x;
    const int wave = tid >> 6;
    const int lane = tid & 63;
    const int bz   = blockIdx.z;
    A += (long)bz * sA;
    B += (long)bz * sB;
    C += (long)bz * sC;
    const long bm = (long)blockIdx.x * 128;
    const long bn = (long)blockIdx.y * 128;

    __shared__ f16 sAt[128 * 32];
    __shared__ f16 sBt[128 * 32];

    // staging: each wave covers 32 rows (2 issues x 16 rows) of each tile.
    // within an issue: lane -> row = lane/4, 16B chunk = lane%4
    const int srow = lane >> 2;
    const int scol = (lane & 3) * 8;
    const f16* gA0 = A + (bm + wave * 32 + srow) * (long)K + scol;
    const f16* gA1 = gA0 + 16 * (long)K;
    const f16* gB0 = B + (bn + wave * 32 + srow) * (long)K + scol;
    const f16* gB1 = gB0 + 16 * (long)K;
    f16* lA0 = &sAt[(wave * 32) * 32];
    f16* lA1 = &sAt[(wave * 32 + 16) * 32];
    f16* lB0 = &sBt[(wave * 32) * 32];
    f16* lB1 = &sBt[(wave * 32 + 16) * 32];

    const int wm = (wave >> 1) * 64;   // wave row offset in tile
    const int wn = (wave & 1) * 64;    // wave col offset in tile
    const int lr = lane & 15;
    const int qd = lane >> 4;

    f32x4 acc[4][4] = {};

    for (int k0 = 0; k0 < K; k0 += 32) {
        GLD16(gA0, lA0); GLD16(gA1, lA1);
        GLD16(gB0, lB0); GLD16(gB1, lB1);
        gA0 += 32; gA1 += 32; gB0 += 32; gB1 += 32;
        __syncthreads();   // drains vmcnt -> LDS tiles complete

        f16x8 af[4], bf[4];
        #pragma unroll
        for (int t = 0; t < 4; ++t) {
            // A-frag: lane holds A[m = lr][k = qd*8 + j]  (ds_read_b128)
            af[t] = *(const f16x8*)&sAt[(wm + t * 16 + lr) * 32 + qd * 8];
            // B-frag (from B^T layout): lane holds B[n = lr][k = qd*8 + j]
            bf[t] = *(const f16x8*)&sBt[(wn + t * 16 + lr) * 32 + qd * 8];
        }
        #pragma unroll
        for (int tm = 0; tm < 4; ++tm)
            #pragma unroll
            for (int tn = 0; tn < 4; ++tn)
                acc[tm][tn] = __builtin_amdgcn_mfma_f32_16x16x32_f16(
                    af[tm], bf[tn], acc[tm][tn], 0, 0, 0);
        __syncthreads();
    }

    // epilogue: C/D layout col = lane&15, row = (lane>>4)*4 + reg
    #pragma unroll
    for (int tn = 0; tn < 4; ++tn) {
        const long col = bn + wn + tn * 16 + lr;
        float bc = (BIAS_MODE == 1) ? bias[col] : 0.f;
        #pragma unroll
        for (int tm = 0; tm < 4; ++tm) {
            #pragma unroll
            for (int r = 0; r < 4; ++r) {
                const long row = bm + wm + tm * 16 + qd * 4 + r;
                float v = acc[tm][tn][r] + bc;
                if (BIAS_MODE == 2) v += bias[row];
                C[row * (long)N + col] = (OutT)v;
            }
        }
    }
}

// ---------------------------------------------------------------------------
// In-place row softmax over f16 scores; one block per row of 2048.
// fp32 math, unscaled (faithful to reference: no 1/sqrt(d), no mask).
// ---------------------------------------------------------------------------
__global__ __launch_bounds__(256)
void softmax_kernel(f16* __restrict__ S)
{
    const long row = blockIdx.x;
    f16* p = S + row * 2048;
    const int tid  = threadIdx.x;
    const int wave = tid >> 6;
    const int lane = tid & 63;

    f16x8 x = *(const f16x8*)&p[tid * 8];
    float v[8];
    float m = -1e30f;
    #pragma unroll
    for (int j = 0; j < 8; ++j) { v[j] = (float)x[j]; m = fmaxf(m, v[j]); }
    #pragma unroll
    for (int off = 32; off > 0; off >>= 1) m = fmaxf(m, __shfl_down(m, off));

    __shared__ float rm[4], rs[4];
    if (lane == 0) rm[wave] = m;
    __syncthreads();
    m = fmaxf(fmaxf(rm[0], rm[1]), fmaxf(rm[2], rm[3]));

    float s = 0.f;
    #pragma unroll
    for (int j = 0; j < 8; ++j) { v[j] = __expf(v[j] - m); s += v[j]; }
    #pragma unroll
    for (int off = 32; off > 0; off >>= 1) s += __shfl_down(s, off);
    if (lane == 0) rs[wave] = s;
    __syncthreads();
    s = rs[0] + rs[1] + rs[2] + rs[3];
    const float inv = 1.0f / s;

    f16x8 y;
    #pragma unroll
    for (int j = 0; j < 8; ++j) y[j] = (f16)(v[j] * inv);
    *(f16x8*)&p[tid * 8] = y;
}

// ---------------------------------------------------------------------------
// fp32 -> f16 converts (sizes are exact multiples of 2048 elements)
// ---------------------------------------------------------------------------
__global__ __launch_bounds__(256)
void cvt_kernel(const float* __restrict__ in, f16* __restrict__ out)
{
    const long i = ((long)blockIdx.x * 256 + threadIdx.x) * 8;
    float4 a = *(const float4*)(in + i);
    float4 b = *(const float4*)(in + i + 4);
    f16x8 o;
    o[0] = (f16)a.x; o[1] = (f16)a.y; o[2] = (f16)a.z; o[3] = (f16)a.w;
    o[4] = (f16)b.x; o[5] = (f16)b.y; o[6] = (f16)b.z; o[7] = (f16)b.w;
    *(f16x8*)&out[i] = o;
}

__global__ __launch_bounds__(256)
void cvt4_kernel(const float* __restrict__ w0, const float* __restrict__ w1,
                 const float* __restrict__ w2, const float* __restrict__ w3,
                 f16* __restrict__ out)
{
    const int sel = blockIdx.y;
    const float* in = (sel == 0) ? w0 : (sel == 1) ? w1 : (sel == 2) ? w2 : w3;
    f16* o = out + (long)sel * 589824;
    const long i = ((long)blockIdx.x * 256 + threadIdx.x) * 8;
    float4 a = *(const float4*)(in + i);
    float4 b = *(const float4*)(in + i + 4);
    f16x8 v;
    v[0] = (f16)a.x; v[1] = (f16)a.y; v[2] = (f16)a.z; v[3] = (f16)a.w;
    v[4] = (f16)b.x; v[5] = (f16)b.y; v[6] = (f16)b.z; v[7] = (f16)b.w;
    *(f16x8*)&o[i] = v;
}

// ---------------------------------------------------------------------------
// B=4, S=2048, D=H=768.  ws layout (bytes):
//   x16   @ 0          12,582,912   (8192 x 768 f16)
//   w16   @ 12582912    4,718,592   (wq,wk,wv,wo f16, 589824 elems each)
//   Q     @ 17301504   12,582,912
//   K     @ 29884416   12,582,912
//   VT    @ 42467328   12,582,912   ([4][768][2048] f16, V transposed)
//   S     @ 55050240   33,554,432   ([4][2048][2048] f16 scores/probs)
//   Y     @ 88604672   12,582,912
// total ~96.5 MB
// ---------------------------------------------------------------------------
extern "C" void kernel_launch(void* const* d_in, const int* in_sizes, int n_in,
                              void* d_out, int out_size, void* d_ws, size_t ws_size,
                              hipStream_t stream)
{
    const float* x  = (const float*)d_in[0];
    const float* wq = (const float*)d_in[1];
    const float* bq = (const float*)d_in[2];
    const float* wk = (const float*)d_in[3];
    const float* bk = (const float*)d_in[4];
    const float* wv = (const float*)d_in[5];
    const float* bv = (const float*)d_in[6];
    const float* wo = (const float*)d_in[7];
    const float* bo = (const float*)d_in[8];

    char* ws = (char*)d_ws;
    f16* x16 = (f16*)(ws + 0);
    f16* w16 = (f16*)(ws + 12582912);
    f16* Q   = (f16*)(ws + 17301504);
    f16* Kb  = (f16*)(ws + 29884416);
    f16* VT  = (f16*)(ws + 42467328);
    f16* S   = (f16*)(ws + 55050240);
    f16* Y   = (f16*)(ws + 88604672);

    f16* wq16 = w16;
    f16* wk16 = w16 + 589824;
    f16* wv16 = w16 + 2 * 589824;
    f16* wo16 = w16 + 3 * 589824;

    // converts
    cvt_kernel<<<3072, 256, 0, stream>>>(x, x16);
    cvt4_kernel<<<dim3(288, 4), 256, 0, stream>>>(wq, wk, wv, wo, w16);

    // Q = x @ wq^T + bq   [8192][768]
    gemm_kernel<f16, 1><<<dim3(64, 6, 1), 256, 0, stream>>>(
        x16, 0, wq16, 0, Q, 0, bq, 768, 768);
    // K = x @ wk^T + bk   [8192][768]
    gemm_kernel<f16, 1><<<dim3(64, 6, 1), 256, 0, stream>>>(
        x16, 0, wk16, 0, Kb, 0, bk, 768, 768);
    // VT[b][h][s] = sum_d wv[h][d] x[b][s][d] + bv[h]   (row-bias)
    gemm_kernel<f16, 2><<<dim3(6, 16, 4), 256, 0, stream>>>(
        wv16, 0, x16, (long)2048 * 768, VT, (long)768 * 2048, bv, 2048, 768);
    // S[b] = Q[b] @ K[b]^T   [2048][2048] per batch
    gemm_kernel<f16, 0><<<dim3(16, 16, 4), 256, 0, stream>>>(
        Q, (long)2048 * 768, Kb, (long)2048 * 768, S, (long)2048 * 2048,
        nullptr, 2048, 768);
    // softmax rows (in place)
    softmax_kernel<<<8192, 256, 0, stream>>>(S);
    // Y[b] = P[b] @ V[b] : A = S (m-major), B = VT (n-major)  [2048][768]
    gemm_kernel<f16, 0><<<dim3(16, 6, 4), 256, 0, stream>>>(
        S, (long)2048 * 2048, VT, (long)768 * 2048, Y, (long)2048 * 768,
        nullptr, 768, 2048);
    // out = Y @ wo^T + bo   [8192][768] fp32
    gemm_kernel<float, 1><<<dim3(64, 6, 1), 256, 0, stream>>>(
        Y, 0, wo16, 0, (float*)d_out, 0, bo, 768, 768);
}

// Round 2
// 264.579 us; speedup vs baseline: 1.0411x; 1.0411x over previous
//
#include <hip/hip_runtime.h>

typedef _Float16 f16;
typedef _Float16 f16x8 __attribute__((ext_vector_type(8)));
typedef float f32x4 __attribute__((ext_vector_type(4)));

// async global->LDS, 16B per lane; LDS dest = wave-uniform base + lane*16
#define GLD16(g, l) __builtin_amdgcn_global_load_lds( \
    (const __attribute__((address_space(1))) void*)(g), \
    (__attribute__((address_space(3))) void*)(l), 16, 0, 0)

// ---------------------------------------------------------------------------
// Generic f16 MFMA GEMM: C[m][n] = sum_k A[m][k] * B[n][k]  (+ bias)
// A: [M][K] row-major f16, B: [N][K] row-major f16 (B^T input layout).
// MODE: 0 = none, 1 = bias[col], 2 = bias[row],
//       3 = split QK: cols 0..767 -> C (+bias), cols 768..1535 -> C2 (+bias2)
// Tiles: BM x BN x 32; 256 threads = 4 waves in 2x2, each wave (BM/2)x(BN/2)
// of 16x16x32_f16 MFMAs. global_load_lds staging with XOR chunk swizzle:
// 16B chunk c of row r is stored at slot c ^ ((r>>1)&3)  -> fragment
// ds_read_b128 hits each bank with exactly 2 lanes (free, m136).
// All M,N multiples of tile and K multiples of 32 -> no edge guards.
// ---------------------------------------------------------------------------
template <typename OutT, int BM, int BN, int MODE>
__global__ __launch_bounds__(256, 4)
void gemm_kernel(const f16* __restrict__ A, long sA,
                 const f16* __restrict__ B, long sB,
                 void* __restrict__ Cv, long sC,
                 void* __restrict__ C2v,
                 const float* __restrict__ bias,
                 const float* __restrict__ bias2,
                 int N, int K)
{
    constexpr int FM = BM / 32;       // A-frags per wave
    constexpr int FN = BN / 32;       // B-frags per wave
    constexpr int IA = BM / 64;       // A staging issues (16 rows each/wave)
    constexpr int IB = BN / 64;
    constexpr int RA = BM / 4;        // A rows staged per wave
    constexpr int RB = BN / 4;

    OutT* C  = (OutT*)Cv;
    OutT* C2 = (OutT*)C2v;
    const int tid  = threadIdx.x;
    const int wave = tid >> 6;
    const int lane = tid & 63;
    const int bz   = blockIdx.z;
    A += (long)bz * sA;
    B += (long)bz * sB;
    C += (long)bz * sC;
    const long bm = (long)blockIdx.x * BM;
    const long bn = (long)blockIdx.y * BN;

    __shared__ f16 sAt[BM * 32];
    __shared__ f16 sBt[BN * 32];

    // staging: lane -> row-in-16 = lane/4, chunk-slot = lane%4.
    // slot p at row r holds global chunk p ^ ((r>>1)&3).
    const int srow = lane >> 2;
    const int sc   = lane & 3;
    const int gch  = (sc ^ ((srow >> 1) & 3)) * 8;   // global chunk offset (f16)

    const f16* gA[IA]; const f16* gB[IB];
    f16* lA[IA]; f16* lB[IB];
    #pragma unroll
    for (int i = 0; i < IA; ++i) {
        gA[i] = A + (bm + wave * RA + i * 16 + srow) * (long)K + gch;
        lA[i] = &sAt[(wave * RA + i * 16) * 32];
    }
    #pragma unroll
    for (int i = 0; i < IB; ++i) {
        gB[i] = B + (bn + wave * RB + i * 16 + srow) * (long)K + gch;
        lB[i] = &sBt[(wave * RB + i * 16) * 32];
    }

    const int wm = (wave >> 1) * (BM / 2);
    const int wn = (wave & 1) * (BN / 2);
    const int lr = lane & 15;
    const int qd = lane >> 4;
    const int swz = (qd ^ ((lr >> 1) & 3)) * 8;      // swizzled k-chunk (f16)

    f32x4 acc[FM][FN] = {};

    for (int k0 = 0; k0 < K; k0 += 32) {
        #pragma unroll
        for (int i = 0; i < IA; ++i) { GLD16(gA[i], lA[i]); gA[i] += 32; }
        #pragma unroll
        for (int i = 0; i < IB; ++i) { GLD16(gB[i], lB[i]); gB[i] += 32; }
        __syncthreads();   // drains vmcnt -> LDS tiles complete

        f16x8 af[FM], bf[FN];
        #pragma unroll
        for (int t = 0; t < FM; ++t)
            af[t] = *(const f16x8*)&sAt[(wm + t * 16 + lr) * 32 + swz];
        #pragma unroll
        for (int t = 0; t < FN; ++t)
            bf[t] = *(const f16x8*)&sBt[(wn + t * 16 + lr) * 32 + swz];
        #pragma unroll
        for (int tm = 0; tm < FM; ++tm)
            #pragma unroll
            for (int tn = 0; tn < FN; ++tn)
                acc[tm][tn] = __builtin_amdgcn_mfma_f32_16x16x32_f16(
                    af[tm], bf[tn], acc[tm][tn], 0, 0, 0);
        __syncthreads();
    }

    // epilogue: C/D layout col = lane&15, row = (lane>>4)*4 + reg
    #pragma unroll
    for (int tn = 0; tn < FN; ++tn) {
        const long col = bn + wn + tn * 16 + lr;
        OutT* dst = C;
        long cc = col, stride = N;
        float bc = 0.f;
        if (MODE == 1) bc = bias[col];
        if (MODE == 3) {
            stride = 768;
            if (col >= 768) { dst = C2; cc = col - 768; bc = bias2[cc]; }
            else            { bc = bias[cc]; }
        }
        #pragma unroll
        for (int tm = 0; tm < FM; ++tm) {
            #pragma unroll
            for (int r = 0; r < 4; ++r) {
                const long row = bm + wm + tm * 16 + qd * 4 + r;
                float v = acc[tm][tn][r] + bc;
                if (MODE == 2) v += bias[row];
                dst[row * stride + cc] = (OutT)v;
            }
        }
    }
}

// ---------------------------------------------------------------------------
// In-place row softmax over f16 scores; one block per row of 2048.
// fp32 math, unscaled (faithful to reference: no 1/sqrt(d), no mask).
// ---------------------------------------------------------------------------
__global__ __launch_bounds__(256)
void softmax_kernel(f16* __restrict__ S)
{
    const long row = blockIdx.x;
    f16* p = S + row * 2048;
    const int tid  = threadIdx.x;
    const int wave = tid >> 6;
    const int lane = tid & 63;

    f16x8 x = *(const f16x8*)&p[tid * 8];
    float v[8];
    float m = -1e30f;
    #pragma unroll
    for (int j = 0; j < 8; ++j) { v[j] = (float)x[j]; m = fmaxf(m, v[j]); }
    #pragma unroll
    for (int off = 32; off > 0; off >>= 1) m = fmaxf(m, __shfl_down(m, off));

    __shared__ float rm[4], rs[4];
    if (lane == 0) rm[wave] = m;
    __syncthreads();
    m = fmaxf(fmaxf(rm[0], rm[1]), fmaxf(rm[2], rm[3]));

    float s = 0.f;
    #pragma unroll
    for (int j = 0; j < 8; ++j) { v[j] = __expf(v[j] - m); s += v[j]; }
    #pragma unroll
    for (int off = 32; off > 0; off >>= 1) s += __shfl_down(s, off);
    if (lane == 0) rs[wave] = s;
    __syncthreads();
    s = rs[0] + rs[1] + rs[2] + rs[3];
    const float inv = 1.0f / s;

    f16x8 y;
    #pragma unroll
    for (int j = 0; j < 8; ++j) y[j] = (f16)(v[j] * inv);
    *(f16x8*)&p[tid * 8] = y;
}

// ---------------------------------------------------------------------------
// fp32 -> f16 converts
// ---------------------------------------------------------------------------
__global__ __launch_bounds__(256)
void cvt_kernel(const float* __restrict__ in, f16* __restrict__ out)
{
    const long i = ((long)blockIdx.x * 256 + threadIdx.x) * 8;
    float4 a = *(const float4*)(in + i);
    float4 b = *(const float4*)(in + i + 4);
    f16x8 o;
    o[0] = (f16)a.x; o[1] = (f16)a.y; o[2] = (f16)a.z; o[3] = (f16)a.w;
    o[4] = (f16)b.x; o[5] = (f16)b.y; o[6] = (f16)b.z; o[7] = (f16)b.w;
    *(f16x8*)&out[i] = o;
}

__global__ __launch_bounds__(256)
void cvt4_kernel(const float* __restrict__ w0, const float* __restrict__ w1,
                 const float* __restrict__ w2, const float* __restrict__ w3,
                 f16* __restrict__ out)
{
    const int sel = blockIdx.y;
    const float* in = (sel == 0) ? w0 : (sel == 1) ? w1 : (sel == 2) ? w2 : w3;
    f16* o = out + (long)sel * 589824;
    const long i = ((long)blockIdx.x * 256 + threadIdx.x) * 8;
    float4 a = *(const float4*)(in + i);
    float4 b = *(const float4*)(in + i + 4);
    f16x8 v;
    v[0] = (f16)a.x; v[1] = (f16)a.y; v[2] = (f16)a.z; v[3] = (f16)a.w;
    v[4] = (f16)b.x; v[5] = (f16)b.y; v[6] = (f16)b.z; v[7] = (f16)b.w;
    *(f16x8*)&o[i] = v;
}

// ---------------------------------------------------------------------------
// B=4, S=2048, D=H=768.  ws layout (bytes):
//   x16 @0  (12.6MB) | w16 @12582912 (4.7MB: wq,wk,wv,wo) | Q @17301504
//   K @29884416 | VT @42467328 ([4][768][2048]) | S @55050240 (33.5MB)
//   Y @88604672      total ~96.5 MB
// ---------------------------------------------------------------------------
extern "C" void kernel_launch(void* const* d_in, const int* in_sizes, int n_in,
                              void* d_out, int out_size, void* d_ws, size_t ws_size,
                              hipStream_t stream)
{
    const float* x  = (const float*)d_in[0];
    const float* wq = (const float*)d_in[1];
    const float* bq = (const float*)d_in[2];
    const float* wk = (const float*)d_in[3];
    const float* bk = (const float*)d_in[4];
    const float* wv = (const float*)d_in[5];
    const float* bv = (const float*)d_in[6];
    const float* wo = (const float*)d_in[7];
    const float* bo = (const float*)d_in[8];

    char* ws = (char*)d_ws;
    f16* x16 = (f16*)(ws + 0);
    f16* w16 = (f16*)(ws + 12582912);
    f16* Q   = (f16*)(ws + 17301504);
    f16* Kb  = (f16*)(ws + 29884416);
    f16* VT  = (f16*)(ws + 42467328);
    f16* S   = (f16*)(ws + 55050240);
    f16* Y   = (f16*)(ws + 88604672);

    f16* wv16 = w16 + 2 * 589824;
    f16* wo16 = w16 + 3 * 589824;

    cvt_kernel<<<3072, 256, 0, stream>>>(x, x16);
    cvt4_kernel<<<dim3(288, 4), 256, 0, stream>>>(wq, wk, wv, wo, w16);

    // fused Q|K projection: B = [wq;wk] (contiguous in w16), N=1536, split out
    gemm_kernel<f16, 128, 128, 3><<<dim3(64, 12, 1), 256, 0, stream>>>(
        x16, 0, w16, 0, Q, 0, Kb, bq, bk, 1536, 768);
    // VT[b][h][s] = sum_d wv[h][d] x[b][s][d] + bv[h]   (row-bias)
    gemm_kernel<f16, 64, 128, 2><<<dim3(12, 16, 4), 256, 0, stream>>>(
        wv16, 0, x16, (long)2048 * 768, VT, (long)768 * 2048, nullptr,
        bv, nullptr, 2048, 768);
    // S[b] = Q[b] @ K[b]^T
    gemm_kernel<f16, 128, 128, 0><<<dim3(16, 16, 4), 256, 0, stream>>>(
        Q, (long)2048 * 768, Kb, (long)2048 * 768, S, (long)2048 * 2048,
        nullptr, nullptr, nullptr, 2048, 768);
    softmax_kernel<<<8192, 256, 0, stream>>>(S);
    // Y[b] = P[b] @ V[b] : A = S, B = VT
    gemm_kernel<f16, 128, 64, 0><<<dim3(16, 12, 4), 256, 0, stream>>>(
        S, (long)2048 * 2048, VT, (long)768 * 2048, Y, (long)2048 * 768,
        nullptr, nullptr, nullptr, 768, 2048);
    // out = Y @ wo^T + bo (fp32 out)
    gemm_kernel<float, 128, 64, 1><<<dim3(64, 12, 1), 256, 0, stream>>>(
        Y, 0, wo16, 0, (float*)d_out, 0, nullptr, bo, nullptr, 768, 768);
}